// Round 4
// baseline (284.535 us; speedup 1.0000x reference)
//
#include <hip/hip_runtime.h>
#include <hip/hip_cooperative_groups.h>
#include <math.h>

namespace cg = cooperative_groups;

#define HWA   22743
#define NBATCH 32
#define NROW  (HWA * NBATCH)   // 727776 (divisible by 4)
#define NC    80
#define TOPK  2048
#define CAND_CAP 4096
#define CONF_THR 0.3f
#define NMS_THR  0.5f
#define NBIN  4096
#define BIN0  0xBE999u   // ford(0.3f) >> 12 ; passing scores land in [BIN0, BIN0+0xE66]
#define NZCAP 224        // LDS-staged suppression rows (224*256B = 57 KB)

// ---- workspace layout (shared host/device) ----
#define O_HIST   ((size_t)0)                         // u32[4096] = 16384 B
#define O_SCAL   (O_HIST + (size_t)NBIN * 4)         // u32[16]   = 64 B
#define O_ROWNZ  (O_SCAL + 64)                       // u64[32]   = 256 B
#define O_KEEPM  (O_ROWNZ + 256)                     // u64[32]   = 256 B
#define O_RANK   (O_KEEPM + 256)                     // u32[CAND_CAP] = 16384 B
#define O_ZEND   (O_RANK + (size_t)CAND_CAP * 4)     // end of zeroed region
#define ZERO_WORDS ((int)(O_ZEND / 4))               // 8336 words zeroed per launch
#define O_CAND   O_ZEND                              // u64[CAND_CAP]
#define O_SKEY   (O_CAND + (size_t)CAND_CAP * 8)     // u32[NROW]
#define O_LABELS (O_SKEY + (size_t)NROW * 4)         // i32[NROW]
#define O_BIDX   (O_LABELS + (size_t)NROW * 4)
#define O_LAB2   (O_BIDX + (size_t)TOPK * 4)
#define O_SCORE  (O_LAB2 + (size_t)TOPK * 4)
#define O_BOX    (O_SCORE + (size_t)TOPK * 4)
#define O_BOXOFF (O_BOX + (size_t)TOPK * 16)
#define O_SUPP   (O_BOXOFF + (size_t)TOPK * 16)      // u64[TOPK*32]

// ---- order-preserving float <-> uint transform ----
__device__ __forceinline__ unsigned int ford(float f) {
    unsigned int u = __float_as_uint(f);
    return (u & 0x80000000u) ? ~u : (u | 0x80000000u);
}
__device__ __forceinline__ float fdec(unsigned int o) {
    unsigned int u = (o & 0x80000000u) ? (o & 0x7fffffffu) : ~o;
    return __uint_as_float(u);
}
__device__ __forceinline__ float sigmoidf(float x) {
    return 1.0f / (1.0f + expf(-x));
}

// ---- 0. zero control buffers: hist + scal + rownz + keepm + rank ----
__global__ void k_zero(unsigned int* __restrict__ z, int nwords) {
    int t = blockIdx.x * 1024 + threadIdx.x;
    if (t < nwords) z[t] = 0u;
}

// ---- 1. per-anchor score/label + compact histogram (u32 score key) ----
// 4 rows per wave, 16 lanes per row. Lane reads float4 (idx 4*sl..4*sl+3)
// plus straggler (idx 64+sl); local argmax ascending-index strictly-greater,
// then 4-step xor-butterfly with (value desc, index asc) lexicographic order
// == exact np.argmax tie semantics.
__global__ void k_score(const float* __restrict__ pconf, const float* __restrict__ pcls,
                        unsigned int* __restrict__ skey, int* __restrict__ labels,
                        unsigned int* __restrict__ hist) {
    int gtid = blockIdx.x * blockDim.x + threadIdx.x;
    int wave = gtid >> 6;
    int lane = threadIdx.x & 63;
    int sub  = lane >> 4;      // row within wave (0..3)
    int sl   = lane & 15;      // sub-lane within row group
    int nwaves = (gridDim.x * blockDim.x) >> 6;
    for (int base = wave * 4; base < NROW; base += nwaves * 4) {
        int i = base + sub;    // NROW % 4 == 0 -> always valid
        const float* row = pcls + (size_t)i * NC;
        float4 q = *(const float4*)(row + 4 * sl);
        float  e = row[64 + sl];
        float v0 = q.x; int i0 = 4 * sl;
        if (q.y > v0) { v0 = q.y; i0 = 4 * sl + 1; }
        if (q.z > v0) { v0 = q.z; i0 = 4 * sl + 2; }
        if (q.w > v0) { v0 = q.w; i0 = 4 * sl + 3; }
        if (e  > v0) { v0 = e;   i0 = 64 + sl; }
        #pragma unroll
        for (int off = 8; off > 0; off >>= 1) {
            float ov = __shfl_xor(v0, off, 64);
            int   oi = __shfl_xor(i0, off, 64);
            if (ov > v0 || (ov == v0 && oi < i0)) { v0 = ov; i0 = oi; }
        }
        if (sl == 0) {
            float cls_conf = sigmoidf(v0);          // = max(sigmoid(pcls)) (monotone)
            float conf     = sigmoidf(pconf[i]);
            float score    = cls_conf * conf;
            float masked   = (score > CONF_THR) ? score : -1.0f;
            unsigned int o = ford(masked);
            skey[i]   = o;
            labels[i] = i0 + 1;
            // sub-threshold rows can never reach top-2048; counting them
            // would funnel all misses into one bin (atomic serialization).
            if (score > CONF_THR) atomicAdd(&hist[(o >> 12) - BIN0], 1u);
        }
    }
}

// ---- 2. cooperative tail: findT + compact + rank + scatprep + supp + scanout ----
// 256 blocks x 256 threads, 4 grid syncs. Phase logic identical to the previous
// separate kernels; findT is computed redundantly per block (sync-free).
__global__ __launch_bounds__(256, 1) void k_tail(char* __restrict__ ws,
        const float* __restrict__ ptxywh, const float* __restrict__ grid_xy,
        const float* __restrict__ anchor_wh, const float* __restrict__ inv_fsize,
        float* __restrict__ out) {
    unsigned int* hist  = (unsigned int*)(ws + O_HIST);
    unsigned int* scal  = (unsigned int*)(ws + O_SCAL);
    unsigned long long* rownz = (unsigned long long*)(ws + O_ROWNZ);
    unsigned long long* keepm = (unsigned long long*)(ws + O_KEEPM);
    unsigned int* rankbuf = (unsigned int*)(ws + O_RANK);
    unsigned long long* cand = (unsigned long long*)(ws + O_CAND);
    unsigned int* skey  = (unsigned int*)(ws + O_SKEY);
    const int* labels   = (const int*)(ws + O_LABELS);
    unsigned int* bidx_a  = (unsigned int*)(ws + O_BIDX);
    unsigned int* label_a = (unsigned int*)(ws + O_LAB2);
    float*        score_a = (float*)(ws + O_SCORE);
    float4*       box_a   = (float4*)(ws + O_BOX);
    float4*       boxoff_a = (float4*)(ws + O_BOXOFF);
    unsigned long long* supp = (unsigned long long*)(ws + O_SUPP);

    cg::grid_group gg = cg::this_grid();
    int tid = threadIdx.x;
    int bid = blockIdx.x;

    // shared memory: sm is the large scratch reused by phases A/C/E/F
    __shared__ unsigned long long sm[NZCAP][32];   // 57344 B
    __shared__ unsigned long long kw[32];
    __shared__ unsigned long long rz[32];
    __shared__ unsigned int sbase[33];
    __shared__ unsigned short rowid[NZCAP];
    __shared__ unsigned int sT;
    __shared__ unsigned long long anyw;

    // ---- Phase A: redundant per-block findT (no grid sync needed) ----
    {
        unsigned int* a = (unsigned int*)sm;       // 256-entry scan array
        unsigned int r[16];
        unsigned int local = 0;
        #pragma unroll
        for (int j = 0; j < 16; ++j) {
            r[j] = hist[4095 - (tid * 16 + j)];    // reversed: descending scores
            local += r[j];
        }
        a[tid] = local;
        __syncthreads();
        for (int off = 1; off < 256; off <<= 1) {
            unsigned int v = a[tid];
            unsigned int ad = (tid >= off) ? a[tid - off] : 0u;
            __syncthreads();
            a[tid] = v + ad;
            __syncthreads();
        }
        unsigned int inc = a[tid];
        unsigned int pre = inc - local;
        unsigned int total = a[255];
        if (tid == 0 && total < TOPK) sT = BIN0;   // degenerate: accept all passing
        if (pre < TOPK && inc >= TOPK) {           // unique crossing thread
            unsigned int c = pre;
            #pragma unroll
            for (int j = 0; j < 16; ++j) {
                unsigned int nc = c + r[j];
                if (c < TOPK && nc >= TOPK) {
                    int p = tid * 16 + j;
                    sT = BIN0 + (unsigned int)(4095 - p);
                }
                c = nc;
            }
        }
        __syncthreads();
    }
    unsigned int T = sT;

    // ---- Phase B: compact (wave-aggregated atomic) ----
    {
        int lane = tid & 63;
        int stride = 256 * 256;
        for (int i = bid * 256 + tid; i < NROW; i += stride) {
            unsigned int o = skey[i];
            bool take = (o >> 12) >= T;
            unsigned long long m = __ballot(take);
            if (m) {
                int leader = __ffsll(m) - 1;
                unsigned int bse = 0;
                if (lane == leader) bse = atomicAdd(&scal[1], (unsigned int)__popcll(m));
                bse = __shfl(bse, leader, 64);
                if (take) {
                    unsigned int pos = bse + (unsigned int)__popcll(m & ((1ull << lane) - 1ull));
                    if (pos < CAND_CAP)
                        cand[pos] = ((unsigned long long)o << 32) | (unsigned int)(~(unsigned int)i);
                }
            }
        }
    }
    gg.sync();

    // ---- Phase C: 2D partial rank (block (ct,st): cand-tile x seg-tile) ----
    {
        unsigned long long* tile = (unsigned long long*)sm;
        unsigned int M = scal[1]; if (M > CAND_CAP) M = CAND_CAP;
        int ct = bid >> 4;
        int st = bid & 15;
        int c  = ct * 256 + tid;
        int jb = st * 256;
        tile[tid] = (jb + tid < (int)M) ? cand[jb + tid] : 0ull;
        __syncthreads();
        if (c < (int)M) {
            unsigned long long myk = cand[c];
            int lim = (int)M - jb; if (lim > 256) lim = 256;
            int r = 0;
            #pragma unroll 8
            for (int j = 0; j < lim; ++j) r += (tile[j] > myk) ? 1 : 0;
            if (r) atomicAdd(&rankbuf[c], (unsigned int)r);
        }
    }
    gg.sync();

    // ---- Phase D: scatter-prepare (decode box at final rank position) ----
    if (bid < CAND_CAP / 256) {
        unsigned int M = scal[1]; if (M > CAND_CAP) M = CAND_CAP;
        int t = bid * 256 + tid;   // 0..4095
        if (t < (int)M) {
            unsigned int rk = rankbuf[t];
            if (rk < TOPK) {
                unsigned long long key = cand[t];
                unsigned int idx = ~(unsigned int)(key & 0xffffffffull);
                unsigned int o = (unsigned int)(key >> 32);
                float score = fdec(o);        // all candidates have score > CONF_THR
                unsigned int b = idx / HWA;
                unsigned int r = idx - b * HWA;
                int lab = labels[idx];
                const float* tp = ptxywh + (size_t)idx * 4;
                float tx = tp[0], ty = tp[1], tw = tp[2], th = tp[3];
                float gx = grid_xy[2 * r], gy = grid_xy[2 * r + 1];
                float aw = anchor_wh[2 * r], ah = anchor_wh[2 * r + 1];
                float invf = inv_fsize[r];
                float cx = (sigmoidf(tx) + gx) * invf;
                float cy = (sigmoidf(ty) + gy) * invf;
                float w = expf(tw) * aw;
                float h = expf(th) * ah;
                float hx = 0.5f * w, hy = 0.5f * h;
                float l = cx - hx, tt = cy - hy, rr = cx + hx, bb = cy + hy;
                l  = fminf(fmaxf(l, 0.0f), 1.0f);
                tt = fminf(fmaxf(tt, 0.0f), 1.0f);
                rr = fminf(fmaxf(rr, 0.0f), 1.0f);
                bb = fminf(fmaxf(bb, 0.0f), 1.0f);
                float off = ((float)b * (float)(NC + 2) + (float)lab) * 4.0f;
                float4 bx; bx.x = l; bx.y = tt; bx.z = rr; bx.w = bb;
                float4 bo; bo.x = l + off; bo.y = tt + off; bo.z = rr + off; bo.w = bb + off;
                box_a[rk] = bx;
                boxoff_a[rk] = bo;
                bidx_a[rk] = b;
                label_a[rk] = (unsigned int)lab;
                score_a[rk] = score;
                atomicOr(&keepm[rk >> 6], 1ull << (rk & 63));
            }
        } else if (t < TOPK) {
            // pad slots (only when M < TOPK): ranks 0..M-1 are bijectively
            // taken, so slots [M,TOPK) are exactly these t.
            float4 z; z.x = 0.0f; z.y = 0.0f; z.z = 0.0f; z.w = 0.0f;
            box_a[t] = z; boxoff_a[t] = z;
            bidx_a[t] = 0u; label_a[t] = 0u; score_a[t] = 0.0f;
        }
    }
    gg.sync();

    // ---- Phase E: suppression bit-matrix, boxes staged once in LDS ----
    {
        float4* sbox = (float4*)sm;               // 2048 * 16 B = 32 KB
        for (int j = tid; j < TOPK; j += 256) sbox[j] = boxoff_a[j];
        __syncthreads();
        for (int r8 = 0; r8 < 8; ++r8) {
            int i = bid * 8 + r8;
            if (tid == 0) anyw = 0ull;
            __syncthreads();
            float4 bi = sbox[i];
            float a1 = (bi.z - bi.x) * (bi.w - bi.y);
            unsigned long long myany = 0ull;
            for (int jt = 0; jt < 8; ++jt) {
                int j = jt * 256 + tid;
                float4 bj = sbox[j];
                float ltx = fmaxf(bi.x, bj.x), lty = fmaxf(bi.y, bj.y);
                float rbx = fminf(bi.z, bj.z), rby = fminf(bi.w, bj.w);
                float wx = rbx - ltx; if (wx < 0.0f) wx = 0.0f;
                float wy = rby - lty; if (wy < 0.0f) wy = 0.0f;
                float inter = wx * wy;
                float a2 = (bj.z - bj.x) * (bj.w - bj.y);
                float iou = inter / (a1 + a2 - inter + 1e-9f);
                unsigned long long m = __ballot(iou > NMS_THR);
                int w = jt * 4 + (tid >> 6);
                if ((tid & 63) == 0) supp[(size_t)i * 32 + w] = m;
                // mask to j > i for the "can this row suppress anyone" test
                unsigned long long masked;
                int base = w * 64;
                if (base + 63 <= i) masked = 0ull;
                else if (base > i) masked = m;
                else {
                    int d = i - base;
                    unsigned long long le = (d == 63) ? ~0ull : ((1ull << (d + 1)) - 1ull);
                    masked = m & ~le;
                }
                if ((tid & 63) == 0) myany |= masked;
            }
            if ((tid & 63) == 0 && myany) atomicOr(&anyw, myany);
            __syncthreads();
            if (tid == 0 && anyw) atomicOr(&rownz[i >> 6], 1ull << (i & 63));
            __syncthreads();
        }
    }
    gg.sync();

    // ---- Phase F: greedy NMS scan from LDS-staged rows + fused output ----
    if (bid == 0) {
        if (tid < 32) { kw[tid] = keepm[tid]; rz[tid] = rownz[tid]; }
        __syncthreads();
        if (tid == 0) {
            unsigned int acc = 0;
            for (int w = 0; w < 32; ++w) { sbase[w] = acc; acc += (unsigned int)__popcll(rz[w]); }
            sbase[32] = acc;
        }
        __syncthreads();
        unsigned int A = sbase[32];
        unsigned int Acap = (A < NZCAP) ? A : NZCAP;
        if (tid < 32) {
            unsigned long long m = rz[tid];
            unsigned int p = sbase[tid];
            while (m) {
                int b = __ffsll(m) - 1;
                if (p < NZCAP) rowid[p] = (unsigned short)(tid * 64 + b);
                ++p;
                m &= m - 1ull;
            }
        }
        __syncthreads();
        for (unsigned int p0 = 0; p0 < Acap; p0 += 8) {
            unsigned int p = p0 + (unsigned int)(tid >> 5);
            if (p < Acap) {
                int i = rowid[p];
                sm[p][tid & 31] = supp[(size_t)i * 32 + (tid & 31)];
            }
        }
        __syncthreads();
        for (int wi = 0; wi < 32; ++wi) {
            unsigned long long processed = 0ull;
            while (true) {
                unsigned long long act = kw[wi] & rz[wi] & ~processed;  // uniform
                if (!act) break;
                int b = __ffsll(act) - 1;
                int i = wi * 64 + b;
                unsigned int p = sbase[wi] +
                    (unsigned int)__popcll(rz[wi] & ((1ull << b) - 1ull));
                if (tid < 32) {
                    unsigned long long rw = (p < NZCAP) ? sm[p][tid]
                                                        : supp[(size_t)i * 32 + tid];
                    if (tid < wi) rw = 0ull;
                    else if (tid == wi) {
                        unsigned long long le = (b == 63) ? ~0ull : ((1ull << (b + 1)) - 1ull);
                        rw &= ~le;                  // only j > i suppressed
                    }
                    kw[tid] &= ~rw;
                }
                __syncthreads();
                processed |= (1ull << b);
            }
        }
        __syncthreads();
        // fused output: ids_b | boxes | labels | scores | keep (all as f32)
        for (int k = tid; k < TOPK; k += 256) {
            bool kp = (kw[k >> 6] >> (k & 63)) & 1ull;
            float4 bx = box_a[k];
            out[k] = (float)bidx_a[k];
            float* ob = out + TOPK + 4 * k;
            ob[0] = kp ? bx.x : 0.0f;
            ob[1] = kp ? bx.y : 0.0f;
            ob[2] = kp ? bx.z : 0.0f;
            ob[3] = kp ? bx.w : 0.0f;
            out[TOPK * 5 + k] = (float)label_a[k];
            out[TOPK * 6 + k] = kp ? score_a[k] : 0.0f;
            out[TOPK * 7 + k] = kp ? 1.0f : 0.0f;
        }
    }
}

extern "C" void kernel_launch(void* const* d_in, const int* in_sizes, int n_in,
                              void* d_out, int out_size, void* d_ws, size_t ws_size,
                              hipStream_t stream) {
    const float* pconf     = (const float*)d_in[0];
    const float* pcls      = (const float*)d_in[1];
    const float* ptxywh    = (const float*)d_in[2];
    const float* grid_xy   = (const float*)d_in[3];
    const float* anchor_wh = (const float*)d_in[4];
    const float* inv_fsize = (const float*)d_in[5];
    float* out = (float*)d_out;

    char* ws = (char*)d_ws;
    unsigned int* skey  = (unsigned int*)(ws + O_SKEY);
    int*          labels = (int*)(ws + O_LABELS);
    unsigned int* hist  = (unsigned int*)(ws + O_HIST);

    k_zero<<<9, 1024, 0, stream>>>((unsigned int*)ws, ZERO_WORDS);
    k_score<<<2048, 256, 0, stream>>>(pconf, pcls, skey, labels, hist);

    void* args[] = {(void*)&ws, (void*)&ptxywh, (void*)&grid_xy,
                    (void*)&anchor_wh, (void*)&inv_fsize, (void*)&out};
    hipLaunchCooperativeKernel((void*)k_tail, dim3(256), dim3(256), args, 0, stream);
}

// Round 5
// 165.825 us; speedup vs baseline: 1.7159x; 1.7159x over previous
//
#include <hip/hip_runtime.h>
#include <math.h>

#define HWA   22743
#define NBATCH 32
#define NROW  (HWA * NBATCH)   // 727776 (divisible by 4)
#define NC    80
#define TOPK  2048
#define CAND_CAP 4096
#define CONF_THR 0.3f
#define NMS_THR  0.5f
#define NBIN  4096
#define BIN0  0xBE999u   // ford(0.3f) >> 12 ; passing scores land in [BIN0, BIN0+0xE66]
#define NZCAP 224        // LDS-staged suppression rows (224*256B = 57 KB)

// ---- order-preserving float <-> uint transform ----
__device__ __forceinline__ unsigned int ford(float f) {
    unsigned int u = __float_as_uint(f);
    return (u & 0x80000000u) ? ~u : (u | 0x80000000u);
}
__device__ __forceinline__ float fdec(unsigned int o) {
    unsigned int u = (o & 0x80000000u) ? (o & 0x7fffffffu) : ~o;
    return __uint_as_float(u);
}
__device__ __forceinline__ float sigmoidf(float x) {
    return 1.0f / (1.0f + expf(-x));
}

// ---- 0. zero control buffers: hist + scal + rownz + keepm + rank ----
__global__ void k_zero(unsigned int* __restrict__ z, int nwords) {
    int t = blockIdx.x * 1024 + threadIdx.x;
    if (t < nwords) z[t] = 0u;
}

// ---- 1. per-anchor score/label + compact histogram (u32 score key) ----
// 4 rows per wave, 16 lanes per row. Lane reads float4 (idx 4*sl..4*sl+3)
// plus straggler (idx 64+sl); local argmax ascending-index strictly-greater,
// then 4-step xor-butterfly with (value desc, index asc) lexicographic order
// == exact np.argmax tie semantics.
__global__ void k_score(const float* __restrict__ pconf, const float* __restrict__ pcls,
                        unsigned int* __restrict__ skey, int* __restrict__ labels,
                        unsigned int* __restrict__ hist) {
    int gtid = blockIdx.x * blockDim.x + threadIdx.x;
    int wave = gtid >> 6;
    int lane = threadIdx.x & 63;
    int sub  = lane >> 4;      // row within wave (0..3)
    int sl   = lane & 15;      // sub-lane within row group
    int nwaves = (gridDim.x * blockDim.x) >> 6;
    for (int base = wave * 4; base < NROW; base += nwaves * 4) {
        int i = base + sub;    // NROW % 4 == 0 -> always valid
        const float* row = pcls + (size_t)i * NC;
        float4 q = *(const float4*)(row + 4 * sl);
        float  e = row[64 + sl];
        float v0 = q.x; int i0 = 4 * sl;
        if (q.y > v0) { v0 = q.y; i0 = 4 * sl + 1; }
        if (q.z > v0) { v0 = q.z; i0 = 4 * sl + 2; }
        if (q.w > v0) { v0 = q.w; i0 = 4 * sl + 3; }
        if (e  > v0) { v0 = e;   i0 = 64 + sl; }
        #pragma unroll
        for (int off = 8; off > 0; off >>= 1) {
            float ov = __shfl_xor(v0, off, 64);
            int   oi = __shfl_xor(i0, off, 64);
            if (ov > v0 || (ov == v0 && oi < i0)) { v0 = ov; i0 = oi; }
        }
        if (sl == 0) {
            float cls_conf = sigmoidf(v0);          // = max(sigmoid(pcls)) (monotone)
            float conf     = sigmoidf(pconf[i]);
            float score    = cls_conf * conf;
            float masked   = (score > CONF_THR) ? score : -1.0f;
            unsigned int o = ford(masked);
            skey[i]   = o;
            labels[i] = i0 + 1;
            // sub-threshold rows can never reach top-2048; counting them
            // would funnel all misses into one bin (atomic serialization).
            if (score > CONF_THR) atomicAdd(&hist[(o >> 12) - BIN0], 1u);
        }
    }
}

// ---- 2+3. fused: per-block redundant findT (L2-resident hist) + compact ----
// Each block independently recomputes the hi-20 threshold from the 4096-bin
// histogram (4096 L2 reads + 256-wide LDS scan; measured essentially free in
// the round-4 coop kernel's Phase A), then runs the wave-aggregated compact.
__global__ __launch_bounds__(256) void k_compactT(const unsigned int* __restrict__ skey,
                          const unsigned int* __restrict__ hist,
                          unsigned long long* __restrict__ cand,
                          unsigned int* __restrict__ scal) {
    __shared__ unsigned int a[256];
    __shared__ unsigned int sT;
    int tid = threadIdx.x;
    {
        unsigned int r[16];
        unsigned int local = 0;
        #pragma unroll
        for (int j = 0; j < 16; ++j) {
            r[j] = hist[4095 - (tid * 16 + j)];    // reversed: descending scores
            local += r[j];
        }
        a[tid] = local;
        __syncthreads();
        for (int off = 1; off < 256; off <<= 1) {
            unsigned int v = a[tid];
            unsigned int ad = (tid >= off) ? a[tid - off] : 0u;
            __syncthreads();
            a[tid] = v + ad;
            __syncthreads();
        }
        unsigned int inc = a[tid];
        unsigned int pre = inc - local;
        unsigned int total = a[255];
        if (tid == 0 && total < TOPK) sT = BIN0;   // degenerate: accept all passing
        if (pre < TOPK && inc >= TOPK) {           // unique crossing thread
            unsigned int c = pre;
            #pragma unroll
            for (int j = 0; j < 16; ++j) {
                unsigned int nc = c + r[j];
                if (c < TOPK && nc >= TOPK) {
                    int p = tid * 16 + j;
                    sT = BIN0 + (unsigned int)(4095 - p);
                }
                c = nc;
            }
        }
        __syncthreads();
    }
    unsigned int T = sT;
    int lane = tid & 63;
    int stride = gridDim.x * blockDim.x;
    for (int i = blockIdx.x * blockDim.x + tid; i < NROW; i += stride) {
        unsigned int o = skey[i];
        bool take = (o >> 12) >= T;
        unsigned long long m = __ballot(take);
        if (m) {
            int leader = __ffsll(m) - 1;
            unsigned int bse = 0;
            if (lane == leader) bse = atomicAdd(&scal[1], (unsigned int)__popcll(m));
            bse = __shfl(bse, leader, 64);
            if (take) {
                unsigned int pos = bse + (unsigned int)__popcll(m & ((1ull << lane) - 1ull));
                if (pos < CAND_CAP)
                    cand[pos] = ((unsigned long long)o << 32) | (unsigned int)(~(unsigned int)i);
            }
        }
    }
}

// ---- 4a. 2D partial rank: block (ct,st) compares cand-tile ct vs seg-tile st ----
// rank[c] = #{j < M : cand[j] > cand[c]} accumulated via atomicAdd over 16 segments.
// Keys unique (index in low bits) -> ranks bijective onto [0,M), descending order,
// ties broken by ascending index (lower i => larger ~i => sorts first). Exact.
__global__ __launch_bounds__(256) void k_rank(const unsigned long long* __restrict__ cand,
                                              const unsigned int* __restrict__ scal,
                                              unsigned int* __restrict__ rankbuf) {
    __shared__ unsigned long long tile[256];
    unsigned int M = scal[1]; if (M > CAND_CAP) M = CAND_CAP;
    int ct = blockIdx.x >> 4;          // candidate tile 0..15
    int st = blockIdx.x & 15;          // segment tile 0..15
    int c  = ct * 256 + threadIdx.x;
    int jb = st * 256;
    tile[threadIdx.x] = (jb + threadIdx.x < (int)M) ? cand[jb + threadIdx.x] : 0ull;
    __syncthreads();
    if (c < (int)M) {
        unsigned long long myk = cand[c];
        int lim = (int)M - jb; if (lim > 256) lim = 256;
        int r = 0;
        #pragma unroll 8
        for (int j = 0; j < lim; ++j) r += (tile[j] > myk) ? 1 : 0;
        if (r) atomicAdd(&rankbuf[c], (unsigned int)r);
    }
}

// ---- 4b+5. scatter-prepare: decode box at final rank position directly ----
__global__ __launch_bounds__(256) void k_scatprep(const unsigned long long* __restrict__ cand,
                          const unsigned int* __restrict__ rankbuf,
                          const unsigned int* __restrict__ scal,
                          const int* __restrict__ labels,
                          const float* __restrict__ ptxywh,
                          const float* __restrict__ grid_xy,
                          const float* __restrict__ anchor_wh,
                          const float* __restrict__ inv_fsize,
                          unsigned int* __restrict__ bidx_a, unsigned int* __restrict__ label_a,
                          float* __restrict__ score_a, float4* __restrict__ box_a,
                          float4* __restrict__ boxoff_a, unsigned long long* __restrict__ keepmask) {
    unsigned int M = scal[1]; if (M > CAND_CAP) M = CAND_CAP;
    int t = blockIdx.x * 256 + threadIdx.x;   // 0..4095
    if (t < (int)M) {
        unsigned int rk = rankbuf[t];
        if (rk < TOPK) {
            unsigned long long key = cand[t];
            unsigned int idx = ~(unsigned int)(key & 0xffffffffull);
            unsigned int o = (unsigned int)(key >> 32);
            float score = fdec(o);            // all candidates have score > CONF_THR
            unsigned int b = idx / HWA;
            unsigned int r = idx - b * HWA;
            int lab = labels[idx];
            const float* tp = ptxywh + (size_t)idx * 4;
            float tx = tp[0], ty = tp[1], tw = tp[2], th = tp[3];
            float gx = grid_xy[2 * r], gy = grid_xy[2 * r + 1];
            float aw = anchor_wh[2 * r], ah = anchor_wh[2 * r + 1];
            float invf = inv_fsize[r];
            float cx = (sigmoidf(tx) + gx) * invf;
            float cy = (sigmoidf(ty) + gy) * invf;
            float w = expf(tw) * aw;
            float h = expf(th) * ah;
            float hx = 0.5f * w, hy = 0.5f * h;
            float l = cx - hx, tt = cy - hy, rr = cx + hx, bb = cy + hy;
            l  = fminf(fmaxf(l, 0.0f), 1.0f);
            tt = fminf(fmaxf(tt, 0.0f), 1.0f);
            rr = fminf(fmaxf(rr, 0.0f), 1.0f);
            bb = fminf(fmaxf(bb, 0.0f), 1.0f);
            float off = ((float)b * (float)(NC + 2) + (float)lab) * 4.0f;
            float4 bx; bx.x = l; bx.y = tt; bx.z = rr; bx.w = bb;
            float4 bo; bo.x = l + off; bo.y = tt + off; bo.z = rr + off; bo.w = bb + off;
            box_a[rk] = bx;
            boxoff_a[rk] = bo;
            bidx_a[rk] = b;
            label_a[rk] = (unsigned int)lab;
            score_a[rk] = score;
            atomicOr(&keepmask[rk >> 6], 1ull << (rk & 63));
        }
    } else if (t < TOPK) {
        // pad slots (only when M < TOPK; unreachable for this input set):
        // ranks 0..M-1 are bijectively taken, so slots [M,TOPK) are exactly these t.
        float4 z; z.x = 0.0f; z.y = 0.0f; z.z = 0.0f; z.w = 0.0f;
        box_a[t] = z; boxoff_a[t] = z;
        bidx_a[t] = 0u; label_a[t] = 0u; score_a[t] = 0.0f;
        // keep bit stays 0 (keepmask pre-zeroed)
    }
}

// ---- 6. suppression bit-matrix + row-nonzero bitmap ----
__global__ void k_supp(const float4* __restrict__ boxoff,
                       unsigned long long* __restrict__ supp,
                       unsigned long long* __restrict__ rownz) {
    __shared__ unsigned long long anyw;
    int i = blockIdx.x;
    if (threadIdx.x == 0) anyw = 0ull;
    __syncthreads();
    float4 bi = boxoff[i];
    float a1 = (bi.z - bi.x) * (bi.w - bi.y);
    unsigned long long myany = 0ull;
    for (int jt = 0; jt < 8; ++jt) {
        int j = jt * 256 + threadIdx.x;
        float4 bj = boxoff[j];
        float ltx = fmaxf(bi.x, bj.x), lty = fmaxf(bi.y, bj.y);
        float rbx = fminf(bi.z, bj.z), rby = fminf(bi.w, bj.w);
        float wx = rbx - ltx; if (wx < 0.0f) wx = 0.0f;
        float wy = rby - lty; if (wy < 0.0f) wy = 0.0f;
        float inter = wx * wy;
        float a2 = (bj.z - bj.x) * (bj.w - bj.y);
        float iou = inter / (a1 + a2 - inter + 1e-9f);
        unsigned long long m = __ballot(iou > NMS_THR);
        int w = jt * 4 + (threadIdx.x >> 6);
        if ((threadIdx.x & 63) == 0) supp[(size_t)i * 32 + w] = m;
        // mask to j > i for the "can this row suppress anyone" test
        unsigned long long masked;
        int base = w * 64;
        if (base + 63 <= i) masked = 0ull;
        else if (base > i) masked = m;
        else {
            int d = i - base;
            unsigned long long le = (d == 63) ? ~0ull : ((1ull << (d + 1)) - 1ull);
            masked = m & ~le;
        }
        if ((threadIdx.x & 63) == 0) myany |= masked;
    }
    if ((threadIdx.x & 63) == 0 && myany) atomicOr(&anyw, myany);
    __syncthreads();
    if (threadIdx.x == 0 && anyw) atomicOr(&rownz[i >> 6], 1ull << (i & 63));
}

// ---- 7. greedy NMS scan from LDS-staged compacted supp rows + fused output ----
__global__ __launch_bounds__(256) void k_scanout(const unsigned long long* __restrict__ supp,
                        const unsigned long long* __restrict__ rownz,
                        const unsigned long long* __restrict__ keepmask,
                        const unsigned int* __restrict__ bidx_a,
                        const unsigned int* __restrict__ label_a,
                        const float* __restrict__ score_a,
                        const float4* __restrict__ box_a,
                        float* __restrict__ out) {
    __shared__ unsigned long long kw[32];
    __shared__ unsigned long long rz[32];
    __shared__ unsigned int base[33];
    __shared__ unsigned short rowid[NZCAP];
    __shared__ unsigned long long sm[NZCAP][32];
    int tid = threadIdx.x;
    if (tid < 32) { kw[tid] = keepmask[tid]; rz[tid] = rownz[tid]; }
    __syncthreads();
    if (tid == 0) {
        unsigned int acc = 0;
        for (int w = 0; w < 32; ++w) { base[w] = acc; acc += (unsigned int)__popcll(rz[w]); }
        base[32] = acc;
    }
    __syncthreads();
    unsigned int A = base[32];
    unsigned int Acap = (A < NZCAP) ? A : NZCAP;
    // build active-row id list (per-word, order = ascending row index)
    if (tid < 32) {
        unsigned long long m = rz[tid];
        unsigned int p = base[tid];
        while (m) {
            int b = __ffsll(m) - 1;
            if (p < NZCAP) rowid[p] = (unsigned short)(tid * 64 + b);
            ++p;
            m &= m - 1ull;
        }
    }
    __syncthreads();
    // stage compacted supp rows: 8 rows per iteration (32 threads per row)
    for (unsigned int p0 = 0; p0 < Acap; p0 += 8) {
        unsigned int p = p0 + (unsigned int)(tid >> 5);
        if (p < Acap) {
            int i = rowid[p];
            sm[p][tid & 31] = supp[(size_t)i * 32 + (tid & 31)];
        }
    }
    __syncthreads();
    // serial greedy scan (same order/masking as the original fori_loop)
    for (int wi = 0; wi < 32; ++wi) {
        unsigned long long processed = 0ull;
        while (true) {
            unsigned long long act = kw[wi] & rz[wi] & ~processed;  // uniform
            if (!act) break;
            int b = __ffsll(act) - 1;
            int i = wi * 64 + b;
            unsigned int p = base[wi] +
                (unsigned int)__popcll(rz[wi] & ((1ull << b) - 1ull));
            if (tid < 32) {
                unsigned long long rw = (p < NZCAP) ? sm[p][tid]
                                                    : supp[(size_t)i * 32 + tid];
                if (tid < wi) rw = 0ull;
                else if (tid == wi) {
                    unsigned long long le = (b == 63) ? ~0ull : ((1ull << (b + 1)) - 1ull);
                    rw &= ~le;                      // only j > i suppressed
                }
                kw[tid] &= ~rw;
            }
            __syncthreads();
            processed |= (1ull << b);
        }
    }
    __syncthreads();
    // fused output: ids_b | boxes | labels | scores | keep (all as f32)
    for (int k = tid; k < TOPK; k += 256) {
        bool kp = (kw[k >> 6] >> (k & 63)) & 1ull;
        float4 bx = box_a[k];
        out[k] = (float)bidx_a[k];
        float* ob = out + TOPK + 4 * k;
        ob[0] = kp ? bx.x : 0.0f;
        ob[1] = kp ? bx.y : 0.0f;
        ob[2] = kp ? bx.z : 0.0f;
        ob[3] = kp ? bx.w : 0.0f;
        out[TOPK * 5 + k] = (float)label_a[k];
        out[TOPK * 6 + k] = kp ? score_a[k] : 0.0f;
        out[TOPK * 7 + k] = kp ? 1.0f : 0.0f;
    }
}

extern "C" void kernel_launch(void* const* d_in, const int* in_sizes, int n_in,
                              void* d_out, int out_size, void* d_ws, size_t ws_size,
                              hipStream_t stream) {
    const float* pconf     = (const float*)d_in[0];
    const float* pcls      = (const float*)d_in[1];
    const float* ptxywh    = (const float*)d_in[2];
    const float* grid_xy   = (const float*)d_in[3];
    const float* anchor_wh = (const float*)d_in[4];
    const float* inv_fsize = (const float*)d_in[5];
    float* out = (float*)d_out;

    char* ws = (char*)d_ws;
    const size_t O_HIST   = 0;                          // u32[4096] = 16384 B
    const size_t O_SCAL   = O_HIST + NBIN * 4;          // u32[16]   = 64 B
    const size_t O_ROWNZ  = O_SCAL + 64;                // u64[32]   = 256 B
    const size_t O_KEEPM  = O_ROWNZ + 256;              // u64[32]   = 256 B
    const size_t O_RANK   = O_KEEPM + 256;              // u32[CAND_CAP] = 16384 B
    const size_t O_ZEND   = O_RANK + (size_t)CAND_CAP * 4;  // end of zeroed region
    const int    ZERO_WORDS = (int)(O_ZEND / 4);        // 8336 words zeroed per launch
    const size_t O_CAND   = O_ZEND;                     // u64[CAND_CAP]
    const size_t O_SKEY   = O_CAND + (size_t)CAND_CAP * 8;  // u32[NROW]
    const size_t O_LABELS = O_SKEY + (size_t)NROW * 4;  // i32[NROW]
    const size_t O_BIDX   = O_LABELS + (size_t)NROW * 4;
    const size_t O_LAB2   = O_BIDX + (size_t)TOPK * 4;
    const size_t O_SCORE  = O_LAB2 + (size_t)TOPK * 4;
    const size_t O_BOX    = O_SCORE + (size_t)TOPK * 4;
    const size_t O_BOXOFF = O_BOX + (size_t)TOPK * 16;
    const size_t O_SUPP   = O_BOXOFF + (size_t)TOPK * 16;     // u64[TOPK*32]

    unsigned int* hist  = (unsigned int*)(ws + O_HIST);
    unsigned int* scal  = (unsigned int*)(ws + O_SCAL);
    unsigned long long* rownz = (unsigned long long*)(ws + O_ROWNZ);
    unsigned long long* keepm = (unsigned long long*)(ws + O_KEEPM);
    unsigned int* rankbuf = (unsigned int*)(ws + O_RANK);
    unsigned long long* cand   = (unsigned long long*)(ws + O_CAND);
    unsigned int* skey  = (unsigned int*)(ws + O_SKEY);
    int*          labels = (int*)(ws + O_LABELS);
    unsigned int* bidx_a  = (unsigned int*)(ws + O_BIDX);
    unsigned int* label_a = (unsigned int*)(ws + O_LAB2);
    float*        score_a = (float*)(ws + O_SCORE);
    float4*       box_a   = (float4*)(ws + O_BOX);
    float4*       boxoff_a = (float4*)(ws + O_BOXOFF);
    unsigned long long* supp = (unsigned long long*)(ws + O_SUPP);

    k_zero<<<9, 1024, 0, stream>>>((unsigned int*)ws, ZERO_WORDS);
    k_score<<<2048, 256, 0, stream>>>(pconf, pcls, skey, labels, hist);
    k_compactT<<<1024, 256, 0, stream>>>(skey, hist, cand, scal);
    k_rank<<<256, 256, 0, stream>>>(cand, scal, rankbuf);
    k_scatprep<<<CAND_CAP / 256, 256, 0, stream>>>(cand, rankbuf, scal, labels, ptxywh,
                                                   grid_xy, anchor_wh, inv_fsize,
                                                   bidx_a, label_a, score_a,
                                                   box_a, boxoff_a, keepm);
    k_supp<<<TOPK, 256, 0, stream>>>(boxoff_a, supp, rownz);
    k_scanout<<<1, 256, 0, stream>>>(supp, rownz, keepm, bidx_a, label_a, score_a,
                                     box_a, out);
}